// Round 3
// baseline (31.022 us; speedup 1.0000x reference)
//
#include <hip/hip_runtime.h>

// out[b,s,e] = cos(x[b,s,1]) * W_dec[e] + b_dec[e]
// x: (8, 4096, 1024) f32; out: (8, 4096, 1024) f32 -> 134 MB pure writes.
// R1 calibration: fillBufferAligned sustains ~7.1 TB/s pure-write (89% peak).
// Strategy: split scattered x-reads (phase A) from the write stream (phase B)
// so phase B is a fill-like pure write stream with L2-hot uniform reads only.

#define EMBED 1024
#define ROWS_PER_BLOCK 16

// Phase A: ws[row] = cos(x[row*EMBED + 1]); 32768 scattered reads, latency-bound.
__global__ __launch_bounds__(256) void vql_gather(const float* __restrict__ x,
                                                  float* __restrict__ ws,
                                                  int nrows) {
    const int i = blockIdx.x * 256 + threadIdx.x;
    if (i < nrows) ws[i] = cosf(x[(size_t)i * EMBED + 1]);
}

// Phase B: pure write stream. cos values come from ws (131 KB, cached).
template <bool GUARD>
__global__ __launch_bounds__(256) void vql_bcast(const float* __restrict__ ws,
                                                 const float* __restrict__ W,
                                                 const float* __restrict__ b,
                                                 float* __restrict__ out,
                                                 int nrows) {
    const int tid = threadIdx.x;  // 256 threads * float4 = 1024 = one row
    const float4 w4 = reinterpret_cast<const float4*>(W)[tid];
    const float4 b4 = reinterpret_cast<const float4*>(b)[tid];
    const int row0 = blockIdx.x * ROWS_PER_BLOCK;

#pragma unroll
    for (int r = 0; r < ROWS_PER_BLOCK; ++r) {
        const int row = row0 + r;
        if (GUARD && row >= nrows) return;
        const float c = ws[row];  // uniform address -> scalar load, L2/L3-hot
        float4 o;
        o.x = fmaf(c, w4.x, b4.x);
        o.y = fmaf(c, w4.y, b4.y);
        o.z = fmaf(c, w4.z, b4.z);
        o.w = fmaf(c, w4.w, b4.w);
        reinterpret_cast<float4*>(out + (size_t)row * EMBED)[tid] = o;
    }
}

// Fallback: original fused single-kernel (if ws too small).
__global__ __launch_bounds__(256) void vql_fused(const float* __restrict__ x,
                                                 const float* __restrict__ W,
                                                 const float* __restrict__ b,
                                                 float* __restrict__ out,
                                                 int nrows) {
    const int tid = threadIdx.x;
    const float4 w4 = reinterpret_cast<const float4*>(W)[tid];
    const float4 b4 = reinterpret_cast<const float4*>(b)[tid];
    const int row0 = blockIdx.x * ROWS_PER_BLOCK;
    for (int r = 0; r < ROWS_PER_BLOCK; ++r) {
        const int row = row0 + r;
        if (row >= nrows) return;
        const float c = cosf(x[(size_t)row * EMBED + 1]);
        float4 o;
        o.x = fmaf(c, w4.x, b4.x);
        o.y = fmaf(c, w4.y, b4.y);
        o.z = fmaf(c, w4.z, b4.z);
        o.w = fmaf(c, w4.w, b4.w);
        reinterpret_cast<float4*>(out + (size_t)row * EMBED)[tid] = o;
    }
}

extern "C" void kernel_launch(void* const* d_in, const int* in_sizes, int n_in,
                              void* d_out, int out_size, void* d_ws, size_t ws_size,
                              hipStream_t stream) {
    const float* x = (const float*)d_in[0];
    const float* W = (const float*)d_in[1];
    const float* b = (const float*)d_in[2];
    float* out = (float*)d_out;

    const int nrows = in_sizes[0] / EMBED;  // 32768

    if (ws_size >= (size_t)nrows * sizeof(float)) {
        float* ws = (float*)d_ws;
        vql_gather<<<(nrows + 255) / 256, 256, 0, stream>>>(x, ws, nrows);

        const int full_blocks = nrows / ROWS_PER_BLOCK;  // 2048 exact here
        if (full_blocks > 0)
            vql_bcast<false><<<full_blocks, 256, 0, stream>>>(ws, W, b, out, nrows);
        const int tail_rows = nrows - full_blocks * ROWS_PER_BLOCK;
        if (tail_rows > 0) {
            const float* ws_t = ws + (size_t)full_blocks * ROWS_PER_BLOCK;
            float* out_t = out + (size_t)full_blocks * ROWS_PER_BLOCK * EMBED;
            vql_bcast<true><<<1, 256, 0, stream>>>(ws_t, W, b, out_t, tail_rows);
        }
    } else {
        const int blocks = (nrows + ROWS_PER_BLOCK - 1) / ROWS_PER_BLOCK;
        vql_fused<<<blocks, 256, 0, stream>>>(x, W, b, out, nrows);
    }
}

// Round 5
// 30.847 us; speedup vs baseline: 1.0057x; 1.0057x over previous
//
#include <hip/hip_runtime.h>

// out[b,s,e] = cos(x[b,s,1]) * W_dec[e] + b_dec[e]
// x: (8, 4096, 1024) f32; out: (8, 4096, 1024) f32 -> 134 MB pure writes.
// Model after R1-R3: kernel ~20 us (write roofline 134MB @ ~7TB/s = 19.6 us)
// + ~7 us fixed graph/launch overhead. R4b: nt stores via clang ext_vector
// (HIP_vector_type rejected by the builtin) + single-kernel exact grid.

#define EMBED 1024
#define ROWS_PER_BLOCK 16

typedef float f32x4 __attribute__((ext_vector_type(4)));

// Exact-grid variant: nrows % ROWS_PER_BLOCK == 0, no guard anywhere.
__global__ __launch_bounds__(256) void vql_exact(const float* __restrict__ x,
                                                 const float* __restrict__ W,
                                                 const float* __restrict__ b,
                                                 float* __restrict__ out) {
    const int tid = threadIdx.x;  // 256 threads * f32x4 = 1024 = one row
    const f32x4 w4 = reinterpret_cast<const f32x4*>(W)[tid];
    const f32x4 b4 = reinterpret_cast<const f32x4*>(b)[tid];
    const int row0 = blockIdx.x * ROWS_PER_BLOCK;

#pragma unroll
    for (int r = 0; r < ROWS_PER_BLOCK; ++r) {
        const int row = row0 + r;
        const float c = cosf(x[(size_t)row * EMBED + 1]);
        f32x4 o;
        o.x = fmaf(c, w4.x, b4.x);
        o.y = fmaf(c, w4.y, b4.y);
        o.z = fmaf(c, w4.z, b4.z);
        o.w = fmaf(c, w4.w, b4.w);
        // nontemporal: bypass L2 write-allocate for the streaming output
        __builtin_nontemporal_store(o, reinterpret_cast<f32x4*>(out + (size_t)row * EMBED) + tid);
    }
}

// Guarded tail variant (not launched at the bench shape).
__global__ __launch_bounds__(256) void vql_tail(const float* __restrict__ x,
                                                const float* __restrict__ W,
                                                const float* __restrict__ b,
                                                float* __restrict__ out,
                                                int nrows) {
    const int tid = threadIdx.x;
    const f32x4 w4 = reinterpret_cast<const f32x4*>(W)[tid];
    const f32x4 b4 = reinterpret_cast<const f32x4*>(b)[tid];
    for (int row = 0; row < nrows; ++row) {
        const float c = cosf(x[(size_t)row * EMBED + 1]);
        f32x4 o;
        o.x = fmaf(c, w4.x, b4.x);
        o.y = fmaf(c, w4.y, b4.y);
        o.z = fmaf(c, w4.z, b4.z);
        o.w = fmaf(c, w4.w, b4.w);
        reinterpret_cast<f32x4*>(out + (size_t)row * EMBED)[tid] = o;
    }
}

extern "C" void kernel_launch(void* const* d_in, const int* in_sizes, int n_in,
                              void* d_out, int out_size, void* d_ws, size_t ws_size,
                              hipStream_t stream) {
    const float* x = (const float*)d_in[0];
    const float* W = (const float*)d_in[1];
    const float* b = (const float*)d_in[2];
    float* out = (float*)d_out;

    const int nrows = in_sizes[0] / EMBED;  // 32768
    const int full_blocks = nrows / ROWS_PER_BLOCK;  // 2048 exact at this shape

    if (full_blocks > 0)
        vql_exact<<<full_blocks, 256, 0, stream>>>(x, W, b, out);

    const int tail_rows = nrows - full_blocks * ROWS_PER_BLOCK;
    if (tail_rows > 0) {
        const float* x_t = x + (size_t)full_blocks * ROWS_PER_BLOCK * EMBED;
        float* out_t = out + (size_t)full_blocks * ROWS_PER_BLOCK * EMBED;
        vql_tail<<<1, 256, 0, stream>>>(x_t, W, b, out_t, tail_rows);
    }
}

// Round 6
// 27.724 us; speedup vs baseline: 1.1190x; 1.1126x over previous
//
#include <hip/hip_runtime.h>

// out[b,s,e] = cos(x[b,s,1]) * W_dec[e] + b_dec[e]
// x: (8, 4096, 1024) f32; out: (8, 4096, 1024) f32 -> 134 MB pure writes.
// Converged model (R1-R5): kernel ~20 us (write roofline 134MB @ ~7TB/s
// = 18.9 us + 4MB read overfetch) + ~7 us fixed graph/measurement overhead.
// R1 (fused, guarded) = 27.66 us best; batched loads / kernel split / nt
// stores all neutral-to-worse. Final: exact-grid fused, normal stores.

#define EMBED 1024
#define ROWS_PER_BLOCK 16

typedef float f32x4 __attribute__((ext_vector_type(4)));

// Exact-grid variant: nrows % ROWS_PER_BLOCK == 0, no guard anywhere.
__global__ __launch_bounds__(256) void vql_exact(const float* __restrict__ x,
                                                 const float* __restrict__ W,
                                                 const float* __restrict__ b,
                                                 float* __restrict__ out) {
    const int tid = threadIdx.x;  // 256 threads * f32x4 = 1024 = one row
    const f32x4 w4 = reinterpret_cast<const f32x4*>(W)[tid];
    const f32x4 b4 = reinterpret_cast<const f32x4*>(b)[tid];
    const int row0 = blockIdx.x * ROWS_PER_BLOCK;

#pragma unroll
    for (int r = 0; r < ROWS_PER_BLOCK; ++r) {
        const int row = row0 + r;
        const float c = cosf(x[(size_t)row * EMBED + 1]);
        f32x4 o;
        o.x = fmaf(c, w4.x, b4.x);
        o.y = fmaf(c, w4.y, b4.y);
        o.z = fmaf(c, w4.z, b4.z);
        o.w = fmaf(c, w4.w, b4.w);
        reinterpret_cast<f32x4*>(out + (size_t)row * EMBED)[tid] = o;
    }
}

// Guarded tail variant (not launched at the bench shape).
__global__ __launch_bounds__(256) void vql_tail(const float* __restrict__ x,
                                                const float* __restrict__ W,
                                                const float* __restrict__ b,
                                                float* __restrict__ out,
                                                int nrows) {
    const int tid = threadIdx.x;
    const f32x4 w4 = reinterpret_cast<const f32x4*>(W)[tid];
    const f32x4 b4 = reinterpret_cast<const f32x4*>(b)[tid];
    for (int row = 0; row < nrows; ++row) {
        const float c = cosf(x[(size_t)row * EMBED + 1]);
        f32x4 o;
        o.x = fmaf(c, w4.x, b4.x);
        o.y = fmaf(c, w4.y, b4.y);
        o.z = fmaf(c, w4.z, b4.z);
        o.w = fmaf(c, w4.w, b4.w);
        reinterpret_cast<f32x4*>(out + (size_t)row * EMBED)[tid] = o;
    }
}

extern "C" void kernel_launch(void* const* d_in, const int* in_sizes, int n_in,
                              void* d_out, int out_size, void* d_ws, size_t ws_size,
                              hipStream_t stream) {
    const float* x = (const float*)d_in[0];
    const float* W = (const float*)d_in[1];
    const float* b = (const float*)d_in[2];
    float* out = (float*)d_out;

    const int nrows = in_sizes[0] / EMBED;  // 32768
    const int full_blocks = nrows / ROWS_PER_BLOCK;  // 2048 exact at this shape

    if (full_blocks > 0)
        vql_exact<<<full_blocks, 256, 0, stream>>>(x, W, b, out);

    const int tail_rows = nrows - full_blocks * ROWS_PER_BLOCK;
    if (tail_rows > 0) {
        const float* x_t = x + (size_t)full_blocks * ROWS_PER_BLOCK * EMBED;
        float* out_t = out + (size_t)full_blocks * ROWS_PER_BLOCK * EMBED;
        vql_tail<<<1, 256, 0, stream>>>(x_t, W, b, out_t, tail_rows);
    }
}